// Round 18
// baseline (172.707 us; speedup 1.0000x reference)
//
#include <hip/hip_runtime.h>
#include <float.h>
#include <math.h>

#define NPTS 16384
#define HDIM 256

// 1-D binning: x ~ N(0,10). Outliers clamped into edge strips; pruning only
// uses "points in bins <= l have x < edge(l+1)" (mirrored for r), which
// clamping preserves.
#define KNB   256
#define KXMIN (-48.0f)
#define KW    0.375f
#define KINVW (1.0f / KW)
#define NHB   64          // hist/scatter blocks

typedef __attribute__((ext_vector_type(8))) short bf16x8;   // 8 bf16 = 4 VGPR
typedef __attribute__((ext_vector_type(4))) float f32x4;    // MFMA acc

__device__ __forceinline__ float silu_f(float z) {
    return z / (1.0f + __expf(-z));
}

__device__ __forceinline__ short f2bf(float f) {            // RNE f32 -> bf16
    unsigned u = __float_as_uint(f);
    u = (u + 0x7FFFu + ((u >> 16) & 1u)) >> 16;
    return (short)u;
}

__device__ __forceinline__ int binof(float x) {
    int b = (int)floorf((x - KXMIN) * KINVW);
    return b < 0 ? 0 : (b > KNB - 1 ? KNB - 1 : b);
}

// sorted-7 insert; exact no-op when V >= a6
#define INS7(a0,a1,a2,a3,a4,a5,a6,V)                \
    {   const float v_ = (V);                       \
        a6 = fmaxf(a5, fminf(a6, v_));              \
        a5 = fmaxf(a4, fminf(a5, v_));              \
        a4 = fmaxf(a3, fminf(a4, v_));              \
        a3 = fmaxf(a2, fminf(a3, v_));              \
        a2 = fmaxf(a1, fminf(a2, v_));              \
        a1 = fmaxf(a0, fminf(a1, v_));              \
        a0 = fminf(a0, v_);                         \
    }

// 6-step butterfly: merges the 64 lanes' sorted-7 lists (DISJOINT point sets
// per lane -- duplicates corrupt ranks, r13 lesson) into the exact top-7 of
// their union, replicated in every lane. Only ever applied to COPIES.
#define MERGE7(a0,a1,a2,a3,a4,a5,a6)                                          \
    _Pragma("unroll")                                                         \
    for (int m = 1; m < 64; m <<= 1) {                                        \
        const float o0 = __shfl_xor(a0, m);                                   \
        const float o1 = __shfl_xor(a1, m);                                   \
        const float o2 = __shfl_xor(a2, m);                                   \
        const float o3 = __shfl_xor(a3, m);                                   \
        const float o4 = __shfl_xor(a4, m);                                   \
        const float o5 = __shfl_xor(a5, m);                                   \
        const float o6 = __shfl_xor(a6, m);                                   \
        const float n0 = fminf(a0, o0);                                       \
        const float n1 = fminf(fminf(a1, o1), fmaxf(a0, o0));                 \
        const float n2 = fminf(fminf(a2, o2),                                 \
                               fminf(fmaxf(a0, o1), fmaxf(a1, o0)));          \
        const float n3 = fminf(fminf(a3, o3),                                 \
                               fminf(fmaxf(a0, o2),                           \
                                     fminf(fmaxf(a1, o1), fmaxf(a2, o0))));   \
        const float n4 = fminf(fminf(a4, o4),                                 \
                               fminf(fminf(fmaxf(a0, o3), fmaxf(a1, o2)),     \
                                     fminf(fmaxf(a2, o1), fmaxf(a3, o0))));   \
        const float n5 = fminf(fminf(a5, o5),                                 \
                               fminf(fminf(fmaxf(a0, o4), fmaxf(a1, o3)),     \
                                     fminf(fmaxf(a2, o2),                     \
                                           fminf(fmaxf(a3, o1),               \
                                                 fmaxf(a4, o0)))));           \
        const float n6 = fminf(fminf(a6, o6),                                 \
                               fminf(fminf(fmaxf(a0, o5), fmaxf(a1, o4)),     \
                                     fminf(fmaxf(a2, o3),                     \
                                           fminf(fmaxf(a3, o2),               \
                                                 fminf(fmaxf(a4, o1),         \
                                                       fmaxf(a5, o0))))));    \
        a0 = n0; a1 = n1; a2 = n2; a3 = n3; a4 = n4; a5 = n5; a6 = n6;        \
    }

// ---------------------------------------------------------------------------
// prepA: blocks 0..47 pack W2/Wd2; blocks 48..111 per-block 256-bin
// histograms, 1 point/thread. (byte-identical to round 17)
// ---------------------------------------------------------------------------
__global__ __launch_bounds__(256) void prepA_kernel(
        const float* __restrict__ xyf,
        const float* __restrict__ W2, const float* __restrict__ Wd2,
        unsigned short* __restrict__ W2p, unsigned short* __restrict__ Wd2p,
        unsigned* __restrict__ histp) {
    const int tid = threadIdx.x;

    if (blockIdx.x < 48) {                        // ---- pack path ----
        const int slot = blockIdx.x * 256 + tid;  // 0..12287
        const float* src;
        unsigned short* dst;
        int s;
        if (slot < 8192) { src = W2;  dst = W2p;  s = slot; }
        else             { src = Wd2; dst = Wd2p; s = slot - 8192; }
        const int t   = s >> 10;
        const int rem = s & 1023;
        const int ct  = rem >> 6;
        const int l   = rem & 63;
        const int k0  = t * 32 + 8 * (l >> 4);
        const int c   = ct * 16 + (l & 15);
        bf16x8 v;
        #pragma unroll
        for (int i = 0; i < 8; ++i)
            v[i] = f2bf(src[(size_t)(k0 + i) * HDIM + c]);
        ((bf16x8*)dst)[s] = v;
        return;
    }

    __shared__ unsigned lh[KNB];
    const int h = blockIdx.x - 48;
    lh[tid] = 0u;
    __syncthreads();
    atomicAdd(&lh[binof(xyf[2 * (h * 256 + tid)])], 1u);
    __syncthreads();
    histp[h * KNB + tid] = lh[tid];
}

// ---------------------------------------------------------------------------
// prepB: 64 scatter blocks, redundant per-block scan, per-slice cursor
// bases; block 0 writes off[]. (byte-identical to round 17)
// ---------------------------------------------------------------------------
__global__ __launch_bounds__(256) void prepB_kernel(
        const float* __restrict__ xyf,
        const unsigned* __restrict__ histp,
        unsigned* __restrict__ off,
        float2* __restrict__ sxy, unsigned* __restrict__ qidx) {
    __shared__ unsigned sc[KNB];
    __shared__ unsigned cur[KNB];
    const int tid = threadIdx.x;
    const int myb = blockIdx.x;

    unsigned tot = 0u, pre = 0u;
    #pragma unroll
    for (int b = 0; b < NHB; ++b) {
        const unsigned v = histp[b * KNB + tid];
        if (b < myb) pre += v;
        tot += v;
    }
    sc[tid] = tot;
    __syncthreads();
    for (int s = 1; s < KNB; s <<= 1) {           // Hillis-Steele scan
        const unsigned v = (tid >= s) ? sc[tid - s] : 0u;
        __syncthreads();
        sc[tid] += v;
        __syncthreads();
    }
    const unsigned excl = sc[tid] - tot;          // global exclusive prefix
    cur[tid] = excl + pre;                        // this block's base in bin
    if (myb == 0) {
        off[tid] = excl;
        if (tid == 0) off[KNB] = (unsigned)NPTS;
    }
    __syncthreads();
    const int i = myb * 256 + tid;                // same slice map as hist
    const float2 p = ((const float2*)xyf)[i];
    const unsigned pos = atomicAdd(&cur[binof(p.x)], 1u);
    sxy[pos]  = p;
    qidx[pos] = (unsigned)i;
}

// ---------------------------------------------------------------------------
// knn_search v12: r15 structure with the phase-3 SERIAL BALLOT-POP REMOVED.
// Diagnosis (r17): stragglers are Y-outliers -- e.g. (0,+35) has 7-NN radius
// ~8 at peak x-density, forcing a ~12000-point x-slab scan that 1-D pruning
// cannot avoid; the per-chunk ballot->ffs->readlane pop chain amplified that
// ~2-3x. Phase 3 now inserts PER-LANE into the private ladders (no cross-
// lane ops in the scan), with the wave-uniform bound ub re-tightened every
// 2 bins by merging a COPY of the ladders (conservative ub >= exact => skip-
// safe; copies only, so lane sets stay disjoint -- r13/r14 discipline), and
// one final copy-merge produces the answer. Phases 1/2 unchanged.
// ---------------------------------------------------------------------------
__global__ __launch_bounds__(512, 8) void knn_search(const float2* __restrict__ sxy,
                                                     const unsigned* __restrict__ qidx,
                                                     const unsigned* __restrict__ off,
                                                     float* __restrict__ md) {
    const int lane = threadIdx.x & 63;
    const int wv   = threadIdx.x >> 6;
    const int qpos = blockIdx.x * 8 + wv;       // sorted position
    const float2 q = sxy[qpos];

    // lane-private sorted top-7 of d^2 (stays private the whole kernel)
    float s0 = FLT_MAX, s1 = FLT_MAX, s2 = FLT_MAX, s3 = FLT_MAX,
          s4 = FLT_MAX, s5 = FLT_MAX, s6 = FLT_MAX;

    // seed bins from the 512-point positional window (wave-uniform)
    const int plo = qpos > 256 ? qpos - 256 : 0;
    const int phi = qpos < NPTS - 256 ? qpos + 255 : NPTS - 1;
    const int lb  = binof(sxy[plo].x);
    const int rb  = binof(sxy[phi].x);

    // phase 1: scan contiguous range [off[lb], off[rb+1]) into lane ladders
    {
        const unsigned o = off[lb], e = off[rb + 1];
        for (unsigned u = o + (unsigned)lane; u < e; u += 64u) {
            const float2 p = sxy[u];
            const float dx = q.x - p.x, dy = q.y - p.y;
            const float d2 = fmaf(dx, dx, dy * dy);
            if (d2 < s6) INS7(s0, s1, s2, s3, s4, s5, s6, d2)
        }
    }

    // phase 2: merge a COPY -> wave-uniform conservative bound ub
    float ub;
    {
        float t0 = s0, t1 = s1, t2 = s2, t3 = s3, t4 = s4, t5 = s5, t6 = s6;
        MERGE7(t0, t1, t2, t3, t4, t5, t6)
        ub = t6;
    }

    // phase 3: outward bin walk, PER-LANE inserts, ub re-tightened /2 bins
    int l = lb - 1, r = rb + 1, since = 0;
    while (l >= 0 || r < KNB) {
        float bl = FLT_MAX, br = FLT_MAX;
        if (l >= 0) {
            const float d = fmaxf(q.x - (KXMIN + (float)(l + 1) * KW), 0.0f);
            bl = d * d;
        }
        if (r < KNB) {
            const float d = fmaxf((KXMIN + (float)r * KW) - q.x, 0.0f);
            br = d * d;
        }
        if (fminf(bl, br) > ub) break;            // conservative => exact-safe
        const int b = (bl <= br) ? l : r;         // uniform choice
        const unsigned o = off[b], e = off[b + 1];
        for (unsigned u = o + (unsigned)lane; u < e; u += 64u) {
            const float2 p = sxy[u];
            const float dx = q.x - p.x, dy = q.y - p.y;
            const float d2 = fmaf(dx, dx, dy * dy);
            if (d2 < s6) INS7(s0, s1, s2, s3, s4, s5, s6, d2)
        }
        if (bl <= br) --l; else ++r;
        if (++since >= 2) {                       // re-tighten bound (copy!)
            float t0 = s0, t1 = s1, t2 = s2, t3 = s3,
                  t4 = s4, t5 = s5, t6 = s6;
            MERGE7(t0, t1, t2, t3, t4, t5, t6)
            ub = t6;
            since = 0;
        }
    }

    // final: merge a copy of the (disjoint) lane ladders -> exact top-7
    float c0 = s0, c1 = s1, c2 = s2, c3 = s3, c4 = s4, c5 = s5, c6 = s6;
    MERGE7(c0, c1, c2, c3, c4, c5, c6)

    if (lane == 0) {
        const float sum = sqrtf(fmaxf(c1, 1e-12f)) + sqrtf(fmaxf(c2, 1e-12f)) +
                          sqrtf(fmaxf(c3, 1e-12f)) + sqrtf(fmaxf(c4, 1e-12f)) +
                          sqrtf(fmaxf(c5, 1e-12f)) + sqrtf(fmaxf(c6, 1e-12f));
        md[qidx[qpos]] = sum * (1.0f / 6.0f);
    }
}

// ---------------------------------------------------------------------------
// Kernel 2 v5 (MFMA) -- byte-identical to rounds 4-17 (measured ~15us, r16).
// ---------------------------------------------------------------------------
#define GEN_A(T)                                                              \
    {                                                                         \
        const int kb = (T) * 32 + klane;                                      \
        const float4 p0 = *(const float4*)(W1 + kb);                          \
        const float4 p1 = *(const float4*)(W1 + kb + 4);                      \
        const float4 r0_ = *(const float4*)(W1 + HDIM + kb);                  \
        const float4 r1_ = *(const float4*)(W1 + HDIM + kb + 4);              \
        const float4 c0_ = *(const float4*)(b1 + kb);                         \
        const float4 c1_ = *(const float4*)(b1 + kb + 4);                     \
        const float pw[8] = {p0.x,p0.y,p0.z,p0.w,p1.x,p1.y,p1.z,p1.w};        \
        const float rw[8] = {r0_.x,r0_.y,r0_.z,r0_.w,r1_.x,r1_.y,r1_.z,r1_.w};\
        const float cw[8] = {c0_.x,c0_.y,c0_.z,c0_.w,c1_.x,c1_.y,c1_.z,c1_.w};\
        _Pragma("unroll")                                                     \
        for (int i = 0; i < 8; ++i)                                           \
            a[i] = f2bf(silu_f(fmaf(q.x, pw[i], fmaf(q.y, rw[i], cw[i]))));   \
    }

#define GEN_G(T)                                                              \
    {                                                                         \
        const int kb = (T) * 32 + klane;                                      \
        const float4 p0 = *(const float4*)(Wd1 + kb);                         \
        const float4 p1 = *(const float4*)(Wd1 + kb + 4);                     \
        const float4 c0_ = *(const float4*)(bd1 + kb);                        \
        const float4 c1_ = *(const float4*)(bd1 + kb + 4);                    \
        const float pw[8] = {p0.x,p0.y,p0.z,p0.w,p1.x,p1.y,p1.z,p1.w};        \
        const float cw[8] = {c0_.x,c0_.y,c0_.z,c0_.w,c1_.x,c1_.y,c1_.z,c1_.w};\
        _Pragma("unroll")                                                     \
        for (int i = 0; i < 8; ++i)                                           \
            a[i] = f2bf(silu_f(fmaf(mdr, pw[i], cw[i])));                     \
    }

#define MFMA8(BUF)                                                            \
    _Pragma("unroll")                                                         \
    for (int j = 0; j < 8; ++j)                                               \
        acc[j] = __builtin_amdgcn_mfma_f32_16x16x32_bf16(a, BUF[j], acc[j], 0, 0, 0);

#define LOADB(BUF, ARR, T)                                                    \
    _Pragma("unroll")                                                         \
    for (int j = 0; j < 8; ++j)                                               \
        BUF[j] = ARR[((T) * 16 + ch * 8 + j) * 64 + lane];

__global__ __launch_bounds__(256, 2) void mlp_kernel(
        const float* __restrict__ xyf,
        const float* __restrict__ W1,  const float* __restrict__ b1,
        const float* __restrict__ b2,
        const float* __restrict__ Wd1, const float* __restrict__ bd1,
        const float* __restrict__ bd2,
        const unsigned short* __restrict__ W2p,
        const unsigned short* __restrict__ Wd2p,
        const float* __restrict__ md,  float* __restrict__ out) {
    const int tid  = threadIdx.x;
    const int lane = tid & 63;
    const int w    = tid >> 6;
    const int r0   = blockIdx.x * 32 + (w >> 1) * 16;
    const int ch   = w & 1;                       // col half: 0 -> 0..127
    const int row  = r0 + (lane & 15);
    const float2 q = ((const float2*)xyf)[row];
    const float mdr = md[row];
    const int klane = 8 * (lane >> 4);

    f32x4 acc[8];
    #pragma unroll
    for (int j = 0; j < 8; ++j) {
        acc[j][0] = 0.0f; acc[j][1] = 0.0f; acc[j][2] = 0.0f; acc[j][3] = 0.0f;
    }

    const bf16x8* B1 = (const bf16x8*)W2p;
    const bf16x8* B2 = (const bf16x8*)Wd2p;
    bf16x8 bA[8], bB[8];
    bf16x8 a;

    LOADB(bA, B1, 0)

    // GEMM1: 8 k-steps of 32, double-buffered bA/bB (all indices static)
    #pragma unroll
    for (int tt = 0; tt < 4; ++tt) {
        {   const int t = 2 * tt;
            GEN_A(t)
            LOADB(bB, B1, t + 1)
            MFMA8(bA)
        }
        {   const int t = 2 * tt + 1;
            GEN_A(t)
            if (t + 1 < 8) { LOADB(bA, B1, t + 1) }
            else           { LOADB(bA, B2, 0)     }   // prefetch GEMM2 t=0
            MFMA8(bB)
        }
    }

    // GEMM2: 4 k-steps of 32
    #pragma unroll
    for (int uu = 0; uu < 2; ++uu) {
        {   const int t = 2 * uu;
            GEN_G(t)
            LOADB(bB, B2, t + 1)
            MFMA8(bA)
        }
        {   const int t = 2 * uu + 1;
            GEN_G(t)
            if (t + 1 < 4) { LOADB(bA, B2, t + 1) }
            MFMA8(bB)
        }
    }

    // epilogue: + b2 + bd2; D map: c = l&15 (per 16-col tile), r = 4*(l>>4)+reg
    const int cb = ch * 128;
    const int rr = r0 + 4 * (lane >> 4);
    #pragma unroll
    for (int j = 0; j < 8; ++j) {
        const int c = cb + j * 16 + (lane & 15);
        const float add = b2[c] + bd2[c];
        out[(size_t)(rr + 0) * HDIM + c] = acc[j][0] + add;
        out[(size_t)(rr + 1) * HDIM + c] = acc[j][1] + add;
        out[(size_t)(rr + 2) * HDIM + c] = acc[j][2] + add;
        out[(size_t)(rr + 3) * HDIM + c] = acc[j][3] + add;
    }
}

extern "C" void kernel_launch(void* const* d_in, const int* in_sizes, int n_in,
                              void* d_out, int out_size, void* d_ws, size_t ws_size,
                              hipStream_t stream) {
    const float* xy  = (const float*)d_in[0];
    const float* W1  = (const float*)d_in[1];
    const float* b1  = (const float*)d_in[2];
    const float* W2  = (const float*)d_in[3];
    const float* b2  = (const float*)d_in[4];
    const float* Wd1 = (const float*)d_in[5];
    const float* bd1 = (const float*)d_in[6];
    const float* Wd2 = (const float*)d_in[7];
    const float* bd2 = (const float*)d_in[8];
    // d_in[9] is k == 6 (fixed by setup_inputs; kernels hard-code top-7)
    float* out = (float*)d_out;

    // workspace layout (bytes):
    //   md / histp [0, 65536)    16384 f32 (histp aliases md; disjoint lifetime)
    //   W2p   [65536,  196608)   65536 bf16
    //   Wd2p  [196608, 262144)   32768 bf16
    //   off   [262144, 263424)   257 u32 (padded)
    //   sxy   [263424, 394496)   16384 float2
    //   qidx  [394496, 460032)   16384 u32
    char* ws = (char*)d_ws;
    float*          md    = (float*)ws;
    unsigned*       histp = (unsigned*)ws;        // alias (see above)
    unsigned short* W2p   = (unsigned short*)(ws + 65536);
    unsigned short* Wd2p  = (unsigned short*)(ws + 196608);
    unsigned*       off   = (unsigned*)(ws + 262144);
    float2*         sxy   = (float2*)(ws + 263424);
    unsigned*       qidx  = (unsigned*)(ws + 394496);

    prepA_kernel<<<48 + NHB, 256, 0, stream>>>(xy, W2, Wd2, W2p, Wd2p, histp);
    prepB_kernel<<<NHB, 256, 0, stream>>>(xy, histp, off, sxy, qidx);
    knn_search<<<NPTS / 8, 512, 0, stream>>>(sxy, qidx, off, md);
    mlp_kernel<<<NPTS / 32, 256, 0, stream>>>(xy, W1, b1, b2, Wd1, bd1, bd2,
                                              W2p, Wd2p, md, out);
}

// Round 19
// 148.650 us; speedup vs baseline: 1.1618x; 1.1618x over previous
//
#include <hip/hip_runtime.h>
#include <float.h>
#include <math.h>

#define NPTS 16384
#define HDIM 256

// 1-D binning: x ~ N(0,10). Outliers clamped into edge strips; pruning only
// uses "points in bins <= l have x < edge(l+1)" (mirrored for r), which
// clamping preserves.
#define KNB   256
#define KXMIN (-48.0f)
#define KW    0.375f
#define KINVW (1.0f / KW)
#define NHB   64          // hist/scatter blocks

typedef __attribute__((ext_vector_type(8))) short bf16x8;   // 8 bf16 = 4 VGPR
typedef __attribute__((ext_vector_type(4))) float f32x4;    // MFMA acc

__device__ __forceinline__ float silu_f(float z) {
    return z / (1.0f + __expf(-z));
}

__device__ __forceinline__ short f2bf(float f) {            // RNE f32 -> bf16
    unsigned u = __float_as_uint(f);
    u = (u + 0x7FFFu + ((u >> 16) & 1u)) >> 16;
    return (short)u;
}

__device__ __forceinline__ float bcast_lane(float x, int l) {
    return __int_as_float(__builtin_amdgcn_readlane(__float_as_int(x), l));
}

__device__ __forceinline__ int binof(float x) {
    int b = (int)floorf((x - KXMIN) * KINVW);
    return b < 0 ? 0 : (b > KNB - 1 ? KNB - 1 : b);
}

// sorted-7 insert; exact no-op when V >= a6
#define INS7(a0,a1,a2,a3,a4,a5,a6,V)                \
    {   const float v_ = (V);                       \
        a6 = fmaxf(a5, fminf(a6, v_));              \
        a5 = fmaxf(a4, fminf(a5, v_));              \
        a4 = fmaxf(a3, fminf(a4, v_));              \
        a3 = fmaxf(a2, fminf(a3, v_));              \
        a2 = fmaxf(a1, fminf(a2, v_));              \
        a1 = fmaxf(a0, fminf(a1, v_));              \
        a0 = fminf(a0, v_);                         \
    }

// ---------------------------------------------------------------------------
// prepA: blocks 0..47 pack W2/Wd2; blocks 48..111 per-block 256-bin
// histograms, 1 point/thread. (byte-identical to round 17)
// ---------------------------------------------------------------------------
__global__ __launch_bounds__(256) void prepA_kernel(
        const float* __restrict__ xyf,
        const float* __restrict__ W2, const float* __restrict__ Wd2,
        unsigned short* __restrict__ W2p, unsigned short* __restrict__ Wd2p,
        unsigned* __restrict__ histp) {
    const int tid = threadIdx.x;

    if (blockIdx.x < 48) {                        // ---- pack path ----
        const int slot = blockIdx.x * 256 + tid;  // 0..12287
        const float* src;
        unsigned short* dst;
        int s;
        if (slot < 8192) { src = W2;  dst = W2p;  s = slot; }
        else             { src = Wd2; dst = Wd2p; s = slot - 8192; }
        const int t   = s >> 10;
        const int rem = s & 1023;
        const int ct  = rem >> 6;
        const int l   = rem & 63;
        const int k0  = t * 32 + 8 * (l >> 4);
        const int c   = ct * 16 + (l & 15);
        bf16x8 v;
        #pragma unroll
        for (int i = 0; i < 8; ++i)
            v[i] = f2bf(src[(size_t)(k0 + i) * HDIM + c]);
        ((bf16x8*)dst)[s] = v;
        return;
    }

    __shared__ unsigned lh[KNB];
    const int h = blockIdx.x - 48;
    lh[tid] = 0u;
    __syncthreads();
    atomicAdd(&lh[binof(xyf[2 * (h * 256 + tid)])], 1u);
    __syncthreads();
    histp[h * KNB + tid] = lh[tid];
}

// ---------------------------------------------------------------------------
// prepB: 64 scatter blocks, redundant per-block scan, per-slice cursor
// bases; block 0 writes off[]. (byte-identical to round 17)
// ---------------------------------------------------------------------------
__global__ __launch_bounds__(256) void prepB_kernel(
        const float* __restrict__ xyf,
        const unsigned* __restrict__ histp,
        unsigned* __restrict__ off,
        float2* __restrict__ sxy, unsigned* __restrict__ qidx) {
    __shared__ unsigned sc[KNB];
    __shared__ unsigned cur[KNB];
    const int tid = threadIdx.x;
    const int myb = blockIdx.x;

    unsigned tot = 0u, pre = 0u;
    #pragma unroll
    for (int b = 0; b < NHB; ++b) {
        const unsigned v = histp[b * KNB + tid];
        if (b < myb) pre += v;
        tot += v;
    }
    sc[tid] = tot;
    __syncthreads();
    for (int s = 1; s < KNB; s <<= 1) {           // Hillis-Steele scan
        const unsigned v = (tid >= s) ? sc[tid - s] : 0u;
        __syncthreads();
        sc[tid] += v;
        __syncthreads();
    }
    const unsigned excl = sc[tid] - tot;          // global exclusive prefix
    cur[tid] = excl + pre;                        // this block's base in bin
    if (myb == 0) {
        off[tid] = excl;
        if (tid == 0) off[KNB] = (unsigned)NPTS;
    }
    __syncthreads();
    const int i = myb * 256 + tid;                // same slice map as hist
    const float2 p = ((const float2*)xyf)[i];
    const unsigned pos = atomicAdd(&cur[binof(p.x)], 1u);
    sxy[pos]  = p;
    qidx[pos] = (unsigned)i;
}

// ---------------------------------------------------------------------------
// knn_search v13 = r15/r17 structure (54us) with 4 POINTS/LANE/ITERATION in
// the phase-1 and phase-3 scan loops. Diagnosis: straggler waves (~40
// y-outliers, concurrent) cost ~125k cycles ~= iterations x ~200cyc L2
// latency -- the per-chunk dependent load chain (un-pipelinable past the
// ballot body) dominates, not VALU. 4 independent float2 loads per iter cut
// latency-exposed iterations 4x. Phase 3 uses the r2-proven min-of-4
// ballot/consume; phase 2 butterfly merge unchanged; r18's per-2-bin
// copy-merge (regression: +24us common-case tax) reverted.
// ---------------------------------------------------------------------------
__global__ __launch_bounds__(512, 8) void knn_search(const float2* __restrict__ sxy,
                                                     const unsigned* __restrict__ qidx,
                                                     const unsigned* __restrict__ off,
                                                     float* __restrict__ md) {
    const int lane = threadIdx.x & 63;
    const int wv   = threadIdx.x >> 6;
    const int qpos = blockIdx.x * 8 + wv;       // sorted position
    const float2 q = sxy[qpos];

    // lane-private sorted top-7 of d^2
    float s0 = FLT_MAX, s1 = FLT_MAX, s2 = FLT_MAX, s3 = FLT_MAX,
          s4 = FLT_MAX, s5 = FLT_MAX, s6 = FLT_MAX;

    // seed bins from the 512-point positional window (wave-uniform)
    const int plo = qpos > 256 ? qpos - 256 : 0;
    const int phi = qpos < NPTS - 256 ? qpos + 255 : NPTS - 1;
    const int lb  = binof(sxy[plo].x);
    const int rb  = binof(sxy[phi].x);

    // phase 1: scan [off[lb], off[rb+1]), 4 pts/lane/iter (ILP on loads)
    {
        const unsigned o = off[lb], e = off[rb + 1];
        for (unsigned u = o + 4u * (unsigned)lane; u < e; u += 256u) {
            #pragma unroll
            for (int j = 0; j < 4; ++j) {
                const unsigned idx = u + (unsigned)j;
                if (idx < e) {
                    const float2 p = sxy[idx];
                    const float dx = q.x - p.x, dy = q.y - p.y;
                    const float d2 = fmaf(dx, dx, dy * dy);
                    if (d2 < s6) INS7(s0, s1, s2, s3, s4, s5, s6, d2)
                }
            }
        }
    }

    // phase 2: butterfly merge -> every lane holds the global top-7 (uniform)
    #pragma unroll
    for (int m = 1; m < 64; m <<= 1) {
        const float o0 = __shfl_xor(s0, m);
        const float o1 = __shfl_xor(s1, m);
        const float o2 = __shfl_xor(s2, m);
        const float o3 = __shfl_xor(s3, m);
        const float o4 = __shfl_xor(s4, m);
        const float o5 = __shfl_xor(s5, m);
        const float o6 = __shfl_xor(s6, m);
        const float n0 = fminf(s0, o0);
        const float n1 = fminf(fminf(s1, o1), fmaxf(s0, o0));
        const float n2 = fminf(fminf(s2, o2),
                               fminf(fmaxf(s0, o1), fmaxf(s1, o0)));
        const float n3 = fminf(fminf(s3, o3),
                               fminf(fmaxf(s0, o2),
                                     fminf(fmaxf(s1, o1), fmaxf(s2, o0))));
        const float n4 = fminf(fminf(s4, o4),
                               fminf(fminf(fmaxf(s0, o3), fmaxf(s1, o2)),
                                     fminf(fmaxf(s2, o1), fmaxf(s3, o0))));
        const float n5 = fminf(fminf(s5, o5),
                               fminf(fminf(fmaxf(s0, o4), fmaxf(s1, o3)),
                                     fminf(fmaxf(s2, o2),
                                           fminf(fmaxf(s3, o1), fmaxf(s4, o0)))));
        const float n6 = fminf(fminf(s6, o6),
                               fminf(fminf(fmaxf(s0, o5), fmaxf(s1, o4)),
                                     fminf(fmaxf(s2, o3),
                                           fminf(fmaxf(s3, o2),
                                                 fminf(fmaxf(s4, o1),
                                                       fmaxf(s5, o0))))));
        s0 = n0; s1 = n1; s2 = n2; s3 = n3; s4 = n4; s5 = n5; s6 = n6;
    }

    // phase 3: outward expansion, 4 pts/lane/iter, min-of-4 ballot-insert
    int l = lb - 1, r = rb + 1;
    while (l >= 0 || r < KNB) {
        float bl = FLT_MAX, br = FLT_MAX;
        if (l >= 0) {
            const float d = fmaxf(q.x - (KXMIN + (float)(l + 1) * KW), 0.0f);
            bl = d * d;
        }
        if (r < KNB) {
            const float d = fmaxf((KXMIN + (float)r * KW) - q.x, 0.0f);
            br = d * d;
        }
        if (fminf(bl, br) > s6) break;                    // all rest farther
        const int b = (bl <= br) ? l : r;
        const unsigned o = off[b], e = off[b + 1];
        for (unsigned u = o + 4u * (unsigned)lane; ; ) {
            const unsigned ubase = u - 4u * (unsigned)lane;   // wave-uniform
            if (ubase >= e) break;
            float ta = FLT_MAX, tb = FLT_MAX, tc = FLT_MAX, td = FLT_MAX;
            if (u + 0 < e) { const float2 p = sxy[u + 0];
                const float dx = q.x - p.x, dy = q.y - p.y;
                ta = fmaf(dx, dx, dy * dy); }
            if (u + 1 < e) { const float2 p = sxy[u + 1];
                const float dx = q.x - p.x, dy = q.y - p.y;
                tb = fmaf(dx, dx, dy * dy); }
            if (u + 2 < e) { const float2 p = sxy[u + 2];
                const float dx = q.x - p.x, dy = q.y - p.y;
                tc = fmaf(dx, dx, dy * dy); }
            if (u + 3 < e) { const float2 p = sxy[u + 3];
                const float dx = q.x - p.x, dy = q.y - p.y;
                td = fmaf(dx, dx, dy * dy); }
            float mv = fminf(fminf(ta, tb), fminf(tc, td));
            unsigned long long m = __ballot(mv < s6);
            while (m) {                              // rare after warmup
                const int L   = __ffsll(m) - 1;
                const float v = bcast_lane(mv, L);
                INS7(s0, s1, s2, s3, s4, s5, s6, v)
                if (lane == L) {                     // consume candidate
                    if      (ta == mv) ta = FLT_MAX;
                    else if (tb == mv) tb = FLT_MAX;
                    else if (tc == mv) tc = FLT_MAX;
                    else               td = FLT_MAX;
                    mv = fminf(fminf(ta, tb), fminf(tc, td));
                }
                m = __ballot(mv < s6);
            }
            u += 256u;
        }
        if (bl <= br) --l; else ++r;
    }

    if (lane == 0) {
        const float sum = sqrtf(fmaxf(s1, 1e-12f)) + sqrtf(fmaxf(s2, 1e-12f)) +
                          sqrtf(fmaxf(s3, 1e-12f)) + sqrtf(fmaxf(s4, 1e-12f)) +
                          sqrtf(fmaxf(s5, 1e-12f)) + sqrtf(fmaxf(s6, 1e-12f));
        md[qidx[qpos]] = sum * (1.0f / 6.0f);
    }
}

// ---------------------------------------------------------------------------
// Kernel 2 v5 (MFMA) -- byte-identical to rounds 4-18 (measured ~15us, r16).
// ---------------------------------------------------------------------------
#define GEN_A(T)                                                              \
    {                                                                         \
        const int kb = (T) * 32 + klane;                                      \
        const float4 p0 = *(const float4*)(W1 + kb);                          \
        const float4 p1 = *(const float4*)(W1 + kb + 4);                      \
        const float4 r0_ = *(const float4*)(W1 + HDIM + kb);                  \
        const float4 r1_ = *(const float4*)(W1 + HDIM + kb + 4);              \
        const float4 c0_ = *(const float4*)(b1 + kb);                         \
        const float4 c1_ = *(const float4*)(b1 + kb + 4);                     \
        const float pw[8] = {p0.x,p0.y,p0.z,p0.w,p1.x,p1.y,p1.z,p1.w};        \
        const float rw[8] = {r0_.x,r0_.y,r0_.z,r0_.w,r1_.x,r1_.y,r1_.z,r1_.w};\
        const float cw[8] = {c0_.x,c0_.y,c0_.z,c0_.w,c1_.x,c1_.y,c1_.z,c1_.w};\
        _Pragma("unroll")                                                     \
        for (int i = 0; i < 8; ++i)                                           \
            a[i] = f2bf(silu_f(fmaf(q.x, pw[i], fmaf(q.y, rw[i], cw[i]))));   \
    }

#define GEN_G(T)                                                              \
    {                                                                         \
        const int kb = (T) * 32 + klane;                                      \
        const float4 p0 = *(const float4*)(Wd1 + kb);                         \
        const float4 p1 = *(const float4*)(Wd1 + kb + 4);                     \
        const float4 c0_ = *(const float4*)(bd1 + kb);                        \
        const float4 c1_ = *(const float4*)(bd1 + kb + 4);                    \
        const float pw[8] = {p0.x,p0.y,p0.z,p0.w,p1.x,p1.y,p1.z,p1.w};        \
        const float cw[8] = {c0_.x,c0_.y,c0_.z,c0_.w,c1_.x,c1_.y,c1_.z,c1_.w};\
        _Pragma("unroll")                                                     \
        for (int i = 0; i < 8; ++i)                                           \
            a[i] = f2bf(silu_f(fmaf(mdr, pw[i], cw[i])));                     \
    }

#define MFMA8(BUF)                                                            \
    _Pragma("unroll")                                                         \
    for (int j = 0; j < 8; ++j)                                               \
        acc[j] = __builtin_amdgcn_mfma_f32_16x16x32_bf16(a, BUF[j], acc[j], 0, 0, 0);

#define LOADB(BUF, ARR, T)                                                    \
    _Pragma("unroll")                                                         \
    for (int j = 0; j < 8; ++j)                                               \
        BUF[j] = ARR[((T) * 16 + ch * 8 + j) * 64 + lane];

__global__ __launch_bounds__(256, 2) void mlp_kernel(
        const float* __restrict__ xyf,
        const float* __restrict__ W1,  const float* __restrict__ b1,
        const float* __restrict__ b2,
        const float* __restrict__ Wd1, const float* __restrict__ bd1,
        const float* __restrict__ bd2,
        const unsigned short* __restrict__ W2p,
        const unsigned short* __restrict__ Wd2p,
        const float* __restrict__ md,  float* __restrict__ out) {
    const int tid  = threadIdx.x;
    const int lane = tid & 63;
    const int w    = tid >> 6;
    const int r0   = blockIdx.x * 32 + (w >> 1) * 16;
    const int ch   = w & 1;                       // col half: 0 -> 0..127
    const int row  = r0 + (lane & 15);
    const float2 q = ((const float2*)xyf)[row];
    const float mdr = md[row];
    const int klane = 8 * (lane >> 4);

    f32x4 acc[8];
    #pragma unroll
    for (int j = 0; j < 8; ++j) {
        acc[j][0] = 0.0f; acc[j][1] = 0.0f; acc[j][2] = 0.0f; acc[j][3] = 0.0f;
    }

    const bf16x8* B1 = (const bf16x8*)W2p;
    const bf16x8* B2 = (const bf16x8*)Wd2p;
    bf16x8 bA[8], bB[8];
    bf16x8 a;

    LOADB(bA, B1, 0)

    // GEMM1: 8 k-steps of 32, double-buffered bA/bB (all indices static)
    #pragma unroll
    for (int tt = 0; tt < 4; ++tt) {
        {   const int t = 2 * tt;
            GEN_A(t)
            LOADB(bB, B1, t + 1)
            MFMA8(bA)
        }
        {   const int t = 2 * tt + 1;
            GEN_A(t)
            if (t + 1 < 8) { LOADB(bA, B1, t + 1) }
            else           { LOADB(bA, B2, 0)     }   // prefetch GEMM2 t=0
            MFMA8(bB)
        }
    }

    // GEMM2: 4 k-steps of 32
    #pragma unroll
    for (int uu = 0; uu < 2; ++uu) {
        {   const int t = 2 * uu;
            GEN_G(t)
            LOADB(bB, B2, t + 1)
            MFMA8(bA)
        }
        {   const int t = 2 * uu + 1;
            GEN_G(t)
            if (t + 1 < 4) { LOADB(bA, B2, t + 1) }
            MFMA8(bB)
        }
    }

    // epilogue: + b2 + bd2; D map: c = l&15 (per 16-col tile), r = 4*(l>>4)+reg
    const int cb = ch * 128;
    const int rr = r0 + 4 * (lane >> 4);
    #pragma unroll
    for (int j = 0; j < 8; ++j) {
        const int c = cb + j * 16 + (lane & 15);
        const float add = b2[c] + bd2[c];
        out[(size_t)(rr + 0) * HDIM + c] = acc[j][0] + add;
        out[(size_t)(rr + 1) * HDIM + c] = acc[j][1] + add;
        out[(size_t)(rr + 2) * HDIM + c] = acc[j][2] + add;
        out[(size_t)(rr + 3) * HDIM + c] = acc[j][3] + add;
    }
}

extern "C" void kernel_launch(void* const* d_in, const int* in_sizes, int n_in,
                              void* d_out, int out_size, void* d_ws, size_t ws_size,
                              hipStream_t stream) {
    const float* xy  = (const float*)d_in[0];
    const float* W1  = (const float*)d_in[1];
    const float* b1  = (const float*)d_in[2];
    const float* W2  = (const float*)d_in[3];
    const float* b2  = (const float*)d_in[4];
    const float* Wd1 = (const float*)d_in[5];
    const float* bd1 = (const float*)d_in[6];
    const float* Wd2 = (const float*)d_in[7];
    const float* bd2 = (const float*)d_in[8];
    // d_in[9] is k == 6 (fixed by setup_inputs; kernels hard-code top-7)
    float* out = (float*)d_out;

    // workspace layout (bytes):
    //   md / histp [0, 65536)    16384 f32 (histp aliases md; disjoint lifetime)
    //   W2p   [65536,  196608)   65536 bf16
    //   Wd2p  [196608, 262144)   32768 bf16
    //   off   [262144, 263424)   257 u32 (padded)
    //   sxy   [263424, 394496)   16384 float2
    //   qidx  [394496, 460032)   16384 u32
    char* ws = (char*)d_ws;
    float*          md    = (float*)ws;
    unsigned*       histp = (unsigned*)ws;        // alias (see above)
    unsigned short* W2p   = (unsigned short*)(ws + 65536);
    unsigned short* Wd2p  = (unsigned short*)(ws + 196608);
    unsigned*       off   = (unsigned*)(ws + 262144);
    float2*         sxy   = (float2*)(ws + 263424);
    unsigned*       qidx  = (unsigned*)(ws + 394496);

    prepA_kernel<<<48 + NHB, 256, 0, stream>>>(xy, W2, Wd2, W2p, Wd2p, histp);
    prepB_kernel<<<NHB, 256, 0, stream>>>(xy, histp, off, sxy, qidx);
    knn_search<<<NPTS / 8, 512, 0, stream>>>(sxy, qidx, off, md);
    mlp_kernel<<<NPTS / 32, 256, 0, stream>>>(xy, W1, b1, b2, Wd1, bd1, bd2,
                                              W2p, Wd2p, md, out);
}